// Round 7
// baseline (2158.206 us; speedup 1.0000x reference)
//
#include <hip/hip_runtime.h>
#include <cstdint>
#include <cstddef>

// Problem constants (fixed by the reference)
constexpr int cB = 2, cS = 1024, cD = 512, cH = 8, cDK = 64, cDFF = 2048;
constexpr int cBS = cB * cS;
constexpr float kNEG = -1e19f;

// NUMERICS RULE (learned R5): the batch-dim layer_norm is a ±0.707 step around
// diff=0; changing any GEMM's fp32 accumulation order flips near-zero diffs and
// cascades O(1) errors to the output. Every GEMM keeps a single fmaf chain with
// k strictly ascending (R4-verified bit pattern). Split-K groupings frozen
// (PV=4, WO=4, FFN2=4, crossQ=4, crossKV=2). The fused softmax (R7) applies
// bit-identical ops (expf(x-m)*inv) on bit-identical stats -> P bits unchanged.

__device__ __forceinline__ float gelu_f(float x)
{
    return 0.5f * x * (1.0f + erff(x * 0.70710678118654752440f));
}

// fused-softmax element transform (PVF: 1 = non-causal, 2 = causal)
template<int PVF>
__device__ __forceinline__ float pvf1(float x, bool masked, int q, int kabs, float rm, float riv)
{
    if (PVF == 2) masked = masked || (q < kabs);
    if (masked) x += kNEG;
    if (PVF == 1) x *= 0.125f;
    return expf(x - rm) * riv;
}

// ============================ SGEMM (fp32 vector, dbuf + async stage) ============
// Tile BM=128 x BN(64|128), BK=16, 256 threads, 8x(BN/16) microtile.
// MODE: 0 = NN (A[m][k], B[k][n]); 1 = TA (A[k][m], B[k][n]); 2 = TB (A[m][k], B[n][k]).
// PVF != 0 (requires MODE==1): A is raw scoresT; softmax applied during staging
// using per-row stats (m, inv) computed by sstats_kernel.
// z = ((g1*G2+g2)*KS + kc); split-K writes plane kc at C + kc*plane.
// K/KS must give an EVEN number of BK steps (true for every call here).
template<int BN, int MODE, bool GELU, int PVF>
__global__ __launch_bounds__(256) void sgemm(
    const float* __restrict__ A, const float* __restrict__ B, float* __restrict__ C,
    const float* __restrict__ bias, const float* __restrict__ resid,
    const float* __restrict__ stats, const unsigned char* __restrict__ padq,
    const unsigned char* __restrict__ padk,
    int K, int KS, int G2, int lda, int ldb, int ldc,
    long long a1, long long a2, long long b1, long long b2,
    long long c1, long long c2, long long plane)
{
    constexpr int BM = 128, BK = 16;
    constexpr int AP = BM + 4, BP = BN + 4;
    constexpr int MN = BN / 16;                      // 4 or 8 cols per thread
    __shared__ float As0[BK][AP], As1[BK][AP];
    __shared__ float Bs0[BK][BP], Bs1[BK][BP];

    const int z = blockIdx.z;
    const int kc = z % KS;
    const int zz = z / KS;
    const int g1 = zz / G2, g2 = zz % G2;
    const float* Ab = A + (long long)g1 * a1 + (long long)g2 * a2;
    const float* Bb = B + (long long)g1 * b1 + (long long)g2 * b2;
    float* Cb = C + (long long)g1 * c1 + (long long)g2 * c2 + (long long)kc * plane;
    const int klen = K / KS, kbase = kc * klen, kend = kbase + klen;
    const int m0 = blockIdx.y * BM, n0 = blockIdx.x * BN;
    const int t = threadIdx.x, tx = t & 15, ty = t >> 4;

    const float* stm = nullptr;
    const unsigned char* pqB = nullptr;
    const unsigned char* pkB = nullptr;
    if (PVF) {
        stm = stats + (long long)zz * 2048;          // zz = b*8+h; [k]{m,inv}
        pqB = padq + (long long)g1 * cS;
        pkB = padk + (long long)g1 * cS;
    }

    float acc[8][MN];
    #pragma unroll
    for (int i = 0; i < 8; ++i)
        #pragma unroll
        for (int j = 0; j < MN; ++j) acc[i][j] = 0.f;

    // ---- staging registers (global -> reg early; reg -> LDS late) ----
    float4 rA0, rA1, rB[BN / 64];
    float2 rst[2]; unsigned char rpk[2]; uchar4 rpq[2];

    auto loadAB = [&](int k0) {
        if (MODE == 1) {                              // TA: A stored [K][M]
            #pragma unroll
            for (int rr = 0; rr < 2; ++rr) {
                const int c = rr * 256 + t, kk = c >> 5, m4 = c & 31;
                float4 v = *(const float4*)&Ab[(long long)(k0 + kk) * lda + m0 + m4 * 4];
                if (rr == 0) rA0 = v; else rA1 = v;
                if (PVF) {
                    const int kabs = k0 + kk;
                    rst[rr] = *(const float2*)&stm[kabs * 2];
                    rpk[rr] = pkB[kabs];
                    rpq[rr] = *(const uchar4*)&pqB[m0 + m4 * 4];
                }
            }
        } else {                                      // A stored [M][K]
            #pragma unroll
            for (int rr = 0; rr < 2; ++rr) {
                const int c = rr * 256 + t, kq = c & 3, mm = c >> 2;
                float4 v = *(const float4*)&Ab[(long long)(m0 + mm) * lda + k0 + kq * 4];
                if (rr == 0) rA0 = v; else rA1 = v;
            }
        }
        if (MODE == 2) {                              // TB: B stored [N][K]
            #pragma unroll
            for (int rr = 0; rr < BN / 64; ++rr) {
                const int c = rr * 256 + t, kq = c & 3, nn = c >> 2;
                rB[rr] = *(const float4*)&Bb[(long long)(n0 + nn) * ldb + k0 + kq * 4];
            }
        } else {                                      // B stored [K][N]
            #pragma unroll
            for (int rr = 0; rr < BN / 64; ++rr) {
                const int c = rr * 256 + t, n4 = c & (BN / 4 - 1), kk = c / (BN / 4);
                rB[rr] = *(const float4*)&Bb[(long long)(k0 + kk) * ldb + n0 + n4 * 4];
            }
        }
    };

    auto writeAB = [&](float (*AS)[AP], float (*BS)[BP], int k0) {
        if (MODE == 1) {
            #pragma unroll
            for (int rr = 0; rr < 2; ++rr) {
                const int c = rr * 256 + t, kk = c >> 5, m4 = c & 31;
                float4 v = (rr == 0) ? rA0 : rA1;
                if (PVF) {
                    const int kabs = k0 + kk, q0 = m0 + m4 * 4;
                    const float rm = rst[rr].x, riv = rst[rr].y;
                    const bool pk = rpk[rr] != 0;
                    v.x = pvf1<PVF>(v.x, pk || rpq[rr].x, q0 + 0, kabs, rm, riv);
                    v.y = pvf1<PVF>(v.y, pk || rpq[rr].y, q0 + 1, kabs, rm, riv);
                    v.z = pvf1<PVF>(v.z, pk || rpq[rr].z, q0 + 2, kabs, rm, riv);
                    v.w = pvf1<PVF>(v.w, pk || rpq[rr].w, q0 + 3, kabs, rm, riv);
                }
                *(float4*)&AS[kk][m4 * 4] = v;
            }
        } else {
            #pragma unroll
            for (int rr = 0; rr < 2; ++rr) {
                const int c = rr * 256 + t, kq = c & 3, mm = c >> 2;
                float4 v = (rr == 0) ? rA0 : rA1;
                AS[kq * 4 + 0][mm] = v.x; AS[kq * 4 + 1][mm] = v.y;
                AS[kq * 4 + 2][mm] = v.z; AS[kq * 4 + 3][mm] = v.w;
            }
        }
        if (MODE == 2) {
            #pragma unroll
            for (int rr = 0; rr < BN / 64; ++rr) {
                const int c = rr * 256 + t, kq = c & 3, nn = c >> 2;
                float4 v = rB[rr];
                BS[kq * 4 + 0][nn] = v.x; BS[kq * 4 + 1][nn] = v.y;
                BS[kq * 4 + 2][nn] = v.z; BS[kq * 4 + 3][nn] = v.w;
            }
        } else {
            #pragma unroll
            for (int rr = 0; rr < BN / 64; ++rr) {
                const int c = rr * 256 + t, n4 = c & (BN / 4 - 1);
                *(float4*)&BS[c / (BN / 4)][n4 * 4] = rB[rr];
            }
        }
    };

    auto compute = [&](float (*AS)[AP], float (*BS)[BP]) {
        #pragma unroll
        for (int kk = 0; kk < BK; ++kk) {
            float a[8], b[MN];
            *(float4*)&a[0] = *(const float4*)&AS[kk][ty * 8];       // 4-addr broadcast: free
            *(float4*)&a[4] = *(const float4*)&AS[kk][ty * 8 + 4];
            *(float4*)&b[0] = *(const float4*)&BS[kk][tx * 4];       // 2-addr/bank: free
            if (MN == 8)
                *(float4*)&b[4] = *(const float4*)&BS[kk][64 + tx * 4];
            #pragma unroll
            for (int i = 0; i < 8; ++i)
                #pragma unroll
                for (int j = 0; j < MN; ++j)
                    acc[i][j] = fmaf(a[i], b[j], acc[i][j]);
        }
    };

    // ---- main loop: 2-deep static double buffer, loads issued before compute ----
    loadAB(kbase);
    writeAB(As0, Bs0, kbase);
    for (int k0 = kbase; k0 < kend; k0 += 2 * BK) {
        loadAB(k0 + BK);                 // issue next-tile loads (even #iters: always valid)
        __syncthreads();                  // As0/Bs0 ready
        compute(As0, Bs0);
        writeAB(As1, Bs1, k0 + BK);       // vmcnt wait lands here, after compute
        const bool more = (k0 + 2 * BK) < kend;
        if (more) loadAB(k0 + 2 * BK);
        __syncthreads();                  // As1/Bs1 ready
        compute(As1, Bs1);
        if (more) writeAB(As0, Bs0, k0 + 2 * BK);
    }

    // ---- epilogue ----
    #pragma unroll
    for (int i = 0; i < 8; ++i) {
        const int row = m0 + ty * 8 + i;
        #pragma unroll
        for (int g = 0; g < MN / 4; ++g) {
            const int col = n0 + g * 64 + tx * 4;
            float4 v;
            v.x = acc[i][g * 4 + 0]; v.y = acc[i][g * 4 + 1];
            v.z = acc[i][g * 4 + 2]; v.w = acc[i][g * 4 + 3];
            if (bias) {
                v.x += bias[col + 0]; v.y += bias[col + 1];
                v.z += bias[col + 2]; v.w += bias[col + 3];
            }
            if (GELU) {
                v.x = gelu_f(v.x); v.y = gelu_f(v.y);
                v.z = gelu_f(v.z); v.w = gelu_f(v.w);
            }
            const long long idx = (long long)row * ldc + col;
            if (resid) {
                float4 rr = *(const float4*)&resid[idx];
                v.x += rr.x; v.y += rr.y; v.z += rr.z; v.w += rr.w;
            }
            *(float4*)&Cb[idx] = v;
        }
    }
}

// ============================ split-K reduces ============================
template<bool GELU>
__global__ __launch_bounds__(256) void reduce_flat(
    const float* __restrict__ parts, float* __restrict__ out, long long n,
    int ks, long long plane, const float* __restrict__ bias, int ldcMask,
    const float* __restrict__ resid)
{
    const long long i = ((long long)blockIdx.x * 256 + threadIdx.x) * 4;
    if (i >= n) return;
    float4 s = {0.f, 0.f, 0.f, 0.f};
    for (int z = 0; z < ks; ++z) {
        float4 v = *(const float4*)&parts[(long long)z * plane + i];
        s.x += v.x; s.y += v.y; s.z += v.z; s.w += v.w;
    }
    if (bias) {
        const int col = (int)(i & ldcMask);
        s.x += bias[col + 0]; s.y += bias[col + 1];
        s.z += bias[col + 2]; s.w += bias[col + 3];
    }
    if (GELU) {
        s.x = gelu_f(s.x); s.y = gelu_f(s.y);
        s.z = gelu_f(s.z); s.w = gelu_f(s.w);
    }
    if (resid) {
        float4 rr = *(const float4*)&resid[i];
        s.x += rr.x; s.y += rr.y; s.z += rr.z; s.w += rr.w;
    }
    *(float4*)&out[i] = s;
}

__global__ __launch_bounds__(256) void reduce_scatter(
    const float* __restrict__ parts, float* __restrict__ out, long long n,
    int ks, long long plane, int logN, int maskN, int ldcOut, int colBase)
{
    const long long i = ((long long)blockIdx.x * 256 + threadIdx.x) * 4;
    if (i >= n) return;
    float4 s = {0.f, 0.f, 0.f, 0.f};
    for (int z = 0; z < ks; ++z) {
        float4 v = *(const float4*)&parts[(long long)z * plane + i];
        s.x += v.x; s.y += v.y; s.z += v.z; s.w += v.w;
    }
    const long long row = i >> logN;
    const int col = (int)(i & maskN);
    *(float4*)&out[row * ldcOut + colBase + col] = s;
}

// ============================ Wc3 (tiled GEMM, all 6 MHAs, one dispatch) ============
__global__ __launch_bounds__(256) void wct_gemm(
    const float* __restrict__ ec, const float* __restrict__ eh,
    const float* __restrict__ dsc, const float* __restrict__ dsh,
    const float* __restrict__ dcc, const float* __restrict__ dch,
    float* __restrict__ Wc3)
{
    constexpr long long LWH = 3LL * 512 * 64;
    __shared__ float As[16][132];
    __shared__ float Bs[16][68];
    const int bid = blockIdx.x;
    const int mt = bid & 3;
    const int zp = bid >> 2;
    const int zi = zp / 24;
    const int ph = zp % 24;
    const int p = ph >> 3, h = ph & 7;
    const int l = zi & 1;
    const float* comb = (zi < 2) ? ec : (zi < 4) ? dsc : dcc;
    const float* head = (zi < 2) ? eh : (zi < 4) ? dsh : dch;
    const float* Ab = comb + l * LWH + (long long)p * 512 * 64 + mt * 128 * 64;
    const float* Bb = head + l * LWH + (long long)ph * 4096;
    float* Cb = Wc3 + (long long)zi * 512 * 1536 + (long long)mt * 128 * 1536 + p * 512 + h * 64;
    const int t = threadIdx.x, tx = t & 15, ty = t >> 4;

    float acc[8][4];
    #pragma unroll
    for (int i = 0; i < 8; ++i)
        #pragma unroll
        for (int j = 0; j < 4; ++j) acc[i][j] = 0.f;

    for (int k0 = 0; k0 < 64; k0 += 16) {
        #pragma unroll
        for (int r = 0; r < 2; ++r) {
            const int c = r * 256 + t, kq = c & 3, mm = c >> 2;
            float4 v = *(const float4*)&Ab[mm * 64 + k0 + kq * 4];
            As[kq * 4 + 0][mm] = v.x; As[kq * 4 + 1][mm] = v.y;
            As[kq * 4 + 2][mm] = v.z; As[kq * 4 + 3][mm] = v.w;
        }
        {
            const int n4 = t & 15, kk = t >> 4;
            *(float4*)&Bs[kk][n4 * 4] = *(const float4*)&Bb[(k0 + kk) * 64 + n4 * 4];
        }
        __syncthreads();
        #pragma unroll
        for (int kk = 0; kk < 16; ++kk) {
            float a[8];
            *(float4*)&a[0] = *(const float4*)&As[kk][ty * 8];
            *(float4*)&a[4] = *(const float4*)&As[kk][ty * 8 + 4];
            float4 b4 = *(const float4*)&Bs[kk][tx * 4];
            const float b[4] = {b4.x, b4.y, b4.z, b4.w};
            #pragma unroll
            for (int i = 0; i < 8; ++i)
                #pragma unroll
                for (int j = 0; j < 4; ++j)
                    acc[i][j] = fmaf(a[i], b[j], acc[i][j]);
        }
        __syncthreads();
    }
    #pragma unroll
    for (int i = 0; i < 8; ++i) {
        const int row = ty * 8 + i;
        float4 v;
        v.x = acc[i][0]; v.y = acc[i][1]; v.z = acc[i][2]; v.w = acc[i][3];
        *(float4*)&Cb[(long long)row * 1536 + tx * 4] = v;
    }
}

// ============================ softmax STATS over QUERY dim ============================
// Bit-identical reductions to the R6 softmax kernel; writes {m, inv} per row instead
// of the normalized row (softmax applied in PV staging).
template<bool CAUSAL>
__global__ __launch_bounds__(256) void sstats_kernel(
    const float* __restrict__ sc, const unsigned char* __restrict__ padq,
    const unsigned char* __restrict__ padk, float scale, float* __restrict__ stats)
{
    const int r = blockIdx.x;             // (b*H + h)*S + k
    const int k = r & (cS - 1);
    const int b = r / (cH * cS);
    const float* row = sc + (long long)r * cS;
    const bool pk = padk[b * cS + k] != 0;
    const int tid = threadIdx.x;
    float4 v4 = reinterpret_cast<const float4*>(row)[tid];
    float vals[4] = {v4.x, v4.y, v4.z, v4.w};
    #pragma unroll
    for (int u = 0; u < 4; ++u) {
        const int q = tid * 4 + u;
        bool masked = pk || (padq[b * cS + q] != 0);
        if (CAUSAL) masked = masked || (q < k);
        float x = vals[u];
        if (masked) x += kNEG;
        if (!CAUSAL) x *= scale;
        vals[u] = x;
    }
    float m = fmaxf(fmaxf(vals[0], vals[1]), fmaxf(vals[2], vals[3]));
    #pragma unroll
    for (int off = 32; off > 0; off >>= 1) m = fmaxf(m, __shfl_down(m, off));
    __shared__ float red[8];
    if ((tid & 63) == 0) red[tid >> 6] = m;
    __syncthreads();
    const float rm = fmaxf(fmaxf(red[0], red[1]), fmaxf(red[2], red[3]));
    float e[4], s = 0.f;
    #pragma unroll
    for (int u = 0; u < 4; ++u) { e[u] = expf(vals[u] - rm); s += e[u]; }
    #pragma unroll
    for (int off = 32; off > 0; off >>= 1) s += __shfl_down(s, off);
    if ((tid & 63) == 0) red[4 + (tid >> 6)] = s;
    __syncthreads();
    if (tid == 0) {
        float inv = 1.0f / (red[4] + red[5] + red[6] + red[7]);
        if (CAUSAL) inv *= scale;
        stats[2 * r] = rm;
        stats[2 * r + 1] = inv;
    }
}

// ============================ batch-dim layer norm (B=2 closed form) ============================
__global__ __launch_bounds__(256) void ln_kernel(const float* __restrict__ x, float* __restrict__ out)
{
    const long long idx = ((long long)blockIdx.x * 256 + threadIdx.x) * 4;
    float4 x0 = *(const float4*)&x[idx];
    float4 x1 = *(const float4*)&x[idx + (long long)cS * cD];
    float4 o;
    {
        const float d0 = x0.x - x1.x; o.x = (0.5f * d0) / (fabsf(d0) * 0.70710678f + 1e-4f);
        const float d1 = x0.y - x1.y; o.y = (0.5f * d1) / (fabsf(d1) * 0.70710678f + 1e-4f);
        const float d2 = x0.z - x1.z; o.z = (0.5f * d2) / (fabsf(d2) * 0.70710678f + 1e-4f);
        const float d3 = x0.w - x1.w; o.w = (0.5f * d3) / (fabsf(d3) * 0.70710678f + 1e-4f);
    }
    *(float4*)&out[idx] = o;
    float4 n;
    n.x = -o.x; n.y = -o.y; n.z = -o.z; n.w = -o.w;
    *(float4*)&out[idx + (long long)cS * cD] = n;
}

// ============================ padding masks ============================
__global__ __launch_bounds__(256) void pad_in_kernel(const float* __restrict__ X, unsigned char* __restrict__ pad)
{
    const int r = blockIdx.x;
    const float* row = X + (long long)r * cD;
    const int tid = threadIdx.x;
    const bool nz = (row[tid] != 0.f) | (row[tid + 256] != 0.f);
    unsigned long long w = __ballot(nz);
    __shared__ unsigned long long sh[4];
    if ((tid & 63) == 0) sh[tid >> 6] = w;
    __syncthreads();
    if (tid == 0) pad[r] = ((sh[0] | sh[1] | sh[2] | sh[3]) == 0ULL) ? 1 : 0;
}

__global__ __launch_bounds__(256) void pad_dec_kernel(const float* __restrict__ outp, unsigned char* __restrict__ pad)
{
    const int r = blockIdx.x;
    const int s = r & (cS - 1);
    const int b = r >> 10;
    if (s == 0) { if (threadIdx.x == 0) pad[r] = 0; return; }
    const float* row = outp + ((long long)b * (cS - 1) + (s - 1)) * cD;
    const int tid = threadIdx.x;
    const bool nz = (row[tid] != 0.f) | (row[tid + 256] != 0.f);
    unsigned long long w = __ballot(nz);
    __shared__ unsigned long long sh[4];
    if ((tid & 63) == 0) sh[tid >> 6] = w;
    __syncthreads();
    if (tid == 0) pad[r] = ((sh[0] | sh[1] | sh[2] | sh[3]) == 0ULL) ? 1 : 0;
}

// ============================ positional encoding ============================
__device__ __forceinline__ float pe_val(int s, int d)
{
    const int i2 = d & ~1;
    const float dv = powf(10000.0f, -(float)i2 / (float)cD);
    const float ang = (float)s * dv;
    return (d & 1) ? cosf(ang) : sinf(ang);
}

__global__ __launch_bounds__(256) void posenc_enc_kernel(const float* __restrict__ X, float* __restrict__ out)
{
    const int r = blockIdx.x;
    const int s = r & (cS - 1);
    const int tid = threadIdx.x;
    #pragma unroll
    for (int u = 0; u < 2; ++u) {
        const int d = tid + 256 * u;
        out[(long long)r * cD + d] = X[(long long)r * cD + d] + pe_val(s, d);
    }
}

__global__ __launch_bounds__(256) void posenc_dec_kernel(const float* __restrict__ outp, float* __restrict__ out)
{
    const int r = blockIdx.x;
    const int s = r & (cS - 1);
    const int b = r >> 10;
    const int tid = threadIdx.x;
    #pragma unroll
    for (int u = 0; u < 2; ++u) {
        const int d = tid + 256 * u;
        const float base = (s == 0) ? 1.0f : outp[((long long)b * (cS - 1) + (s - 1)) * cD + d];
        out[(long long)r * cD + d] = base + pe_val(s, d);
    }
}

// ============================ final masked slice ============================
__global__ __launch_bounds__(256) void final_kernel(const float* __restrict__ cur,
                                                    const unsigned char* __restrict__ pad,
                                                    float* __restrict__ out)
{
    const int r = blockIdx.x;
    const int b = r / (cS - 1);
    const int s = r - b * (cS - 1) + 1;
    const int tid = threadIdx.x;
    const bool p = pad[b * cS + s] != 0;
    #pragma unroll
    for (int u = 0; u < 2; ++u) {
        const int d = tid + 256 * u;
        out[(long long)r * cD + d] = p ? 0.0f : cur[((long long)b * cS + s) * cD + d];
    }
}

// ============================ host orchestration ============================
struct Ws {
    float *t0, *t1, *t2, *t3, *wc3a, *qkv, *att, *parts, *sc, *ffn, *stats;
    unsigned char *pin, *pout;
};

static void run_mha(hipStream_t st, const Ws& w, int mhaIdx,
                    const float* xq, const float* xkv,
                    const float* WO, const float* bO,
                    const unsigned char* padq, const unsigned char* padk,
                    bool causal, const float* resid, float* outR)
{
    const long long M1 = 1048576;
    const float* wc3 = w.wc3a + (long long)mhaIdx * 512 * 1536;
    if (xq == xkv) {
        // fused QKV (NN, BN=64, KS=1, grid 384)
        sgemm<64, 0, false, 0><<<dim3(24, 16, 1), 256, 0, st>>>(
            xq, wc3, w.qkv, nullptr, nullptr, nullptr, nullptr, nullptr,
            512, 1, 1, 512, 1536, 1536, 0, 0, 0, 0, 0, 0, 0);
    } else {
        // cross: Q (split-K=4), K/V (split-K=2)
        sgemm<64, 0, false, 0><<<dim3(8, 16, 4), 256, 0, st>>>(
            xq, wc3, w.parts, nullptr, nullptr, nullptr, nullptr, nullptr,
            512, 4, 1, 512, 1536, 512, 0, 0, 0, 0, 0, 0, M1);
        reduce_scatter<<<dim3(1024), 256, 0, st>>>(w.parts, w.qkv, M1, 4, M1, 9, 511, 1536, 0);
        sgemm<64, 0, false, 0><<<dim3(16, 16, 2), 256, 0, st>>>(
            xkv, wc3 + 512, w.parts, nullptr, nullptr, nullptr, nullptr, nullptr,
            512, 2, 1, 512, 1536, 1024, 0, 0, 0, 0, 0, 0, 2 * M1);
        reduce_scatter<<<dim3(2048), 256, 0, st>>>(w.parts, w.qkv, 2 * M1, 2, 2 * M1, 10, 1023, 1536, 512);
    }
    // scoresT[b,h][k][q] = K . Q (TB, BN=128, grid 1024)
    sgemm<128, 2, false, 0><<<dim3(8, 8, 16), 256, 0, st>>>(
        w.qkv + 512, w.qkv, w.sc, nullptr, nullptr, nullptr, nullptr, nullptr,
        64, 1, 8, 1536, 1536, 1024,
        1024LL * 1536, 64, 1024LL * 1536, 64, 8 * M1, M1, 0);
    // softmax stats over q (bit-identical reductions to the old softmax kernel)
    {
        dim3 g(cB * cH * cS), blk(256);
        if (causal) sstats_kernel<true><<<g, blk, 0, st>>>(w.sc, padq, padk, 0.125f, w.stats);
        else        sstats_kernel<false><<<g, blk, 0, st>>>(w.sc, padq, padk, 0.125f, w.stats);
    }
    // PV (TA x NN, BN=64, split-K=4, grid 512) with softmax fused into A-staging
    if (causal) {
        sgemm<64, 1, false, 2><<<dim3(1, 8, 64), 256, 0, st>>>(
            w.sc, w.qkv + 1024, w.parts, nullptr, nullptr, w.stats, padq, padk,
            1024, 4, 8, 1024, 1536, 512,
            8 * M1, M1, 1024LL * 1536, 64, 1024LL * 512, 64, M1);
    } else {
        sgemm<64, 1, false, 1><<<dim3(1, 8, 64), 256, 0, st>>>(
            w.sc, w.qkv + 1024, w.parts, nullptr, nullptr, w.stats, padq, padk,
            1024, 4, 8, 1024, 1536, 512,
            8 * M1, M1, 1024LL * 1536, 64, 1024LL * 512, 64, M1);
    }
    reduce_flat<false><<<dim3(1024), 256, 0, st>>>(w.parts, w.att, M1, 4, M1, nullptr, 0, nullptr);
    // WO (NN, BN=64, split-K=4, grid 512)
    sgemm<64, 0, false, 0><<<dim3(8, 16, 4), 256, 0, st>>>(
        w.att, WO, w.parts, nullptr, nullptr, nullptr, nullptr, nullptr,
        512, 4, 1, 512, 512, 512, 0, 0, 0, 0, 0, 0, M1);
    reduce_flat<false><<<dim3(1024), 256, 0, st>>>(w.parts, outR, M1, 4, M1, bO, 511, resid);
}

extern "C" void kernel_launch(void* const* d_in, const int* in_sizes, int n_in,
                              void* d_out, int out_size, void* d_ws, size_t ws_size,
                              hipStream_t stream)
{
    const float* X       = (const float*)d_in[0];
    const float* outp    = (const float*)d_in[1];
    const float* e_comb  = (const float*)d_in[2];
    const float* e_head  = (const float*)d_in[3];
    const float* e_WO    = (const float*)d_in[4];
    const float* e_bO    = (const float*)d_in[5];
    const float* e_W1    = (const float*)d_in[6];
    const float* e_W2    = (const float*)d_in[7];
    const float* ds_comb = (const float*)d_in[8];
    const float* ds_head = (const float*)d_in[9];
    const float* ds_WO   = (const float*)d_in[10];
    const float* ds_bO   = (const float*)d_in[11];
    const float* dc_comb = (const float*)d_in[12];
    const float* dc_head = (const float*)d_in[13];
    const float* dc_WO   = (const float*)d_in[14];
    const float* dc_bO   = (const float*)d_in[15];
    const float* d_W1    = (const float*)d_in[16];
    const float* d_W2    = (const float*)d_in[17];
    float* Y = (float*)d_out;

    Ws w;
    float* p = (float*)d_ws;
    const long long M1 = 1048576;
    w.t0   = p; p += M1;
    w.t1   = p; p += M1;
    w.t2   = p; p += M1;
    w.t3   = p; p += M1;
    w.wc3a = p; p += 6LL * 512 * 1536;      // 4,718,592
    w.qkv  = p; p += 2048LL * 1536;         // 3,145,728
    w.att  = p; p += M1;
    w.parts= p; p += 4 * M1;                // split-K compact planes (PV/WO/FFN2/cross)
    w.sc   = p; p += 16LL * M1;             // 64 MB scores
    w.ffn  = w.sc;                          // [2048][2048] overlays sc[0..4M1]
    w.stats= p; p += 2LL * cB * cH * cS;    // 32768 floats: {m, inv} per score row
    w.pin  = (unsigned char*)p;
    w.pout = w.pin + cB * cS;

    // ---- prep ----
    pad_in_kernel <<<dim3(cB * cS), 256, 0, stream>>>(X, w.pin);
    pad_dec_kernel<<<dim3(cB * cS), 256, 0, stream>>>(outp, w.pout);
    posenc_enc_kernel<<<dim3(cB * cS), 256, 0, stream>>>(X, w.t0);
    posenc_dec_kernel<<<dim3(cB * cS), 256, 0, stream>>>(outp, w.t3);
    wct_gemm<<<dim3(576), 256, 0, stream>>>(e_comb, e_head, ds_comb, ds_head, dc_comb, dc_head, w.wc3a);

    const dim3 lnGrid(cS * cD / 1024);

    // ---- encoder ----
    for (int i = 0; i < 2; ++i) {
        ln_kernel<<<lnGrid, 256, 0, stream>>>(w.t0, w.t1);
        run_mha(stream, w, i, w.t1, w.t1,
                e_WO + (long long)i * cD * cD, e_bO + i * cD,
                w.pin, w.pin, false, w.t1, w.t2);
        ln_kernel<<<lnGrid, 256, 0, stream>>>(w.t2, w.t1);
        sgemm<64, 0, true, 0><<<dim3(32, 16, 1), 256, 0, stream>>>(
            w.t1, e_W1 + (long long)i * cD * cDFF, w.ffn, nullptr, nullptr, nullptr, nullptr, nullptr,
            512, 1, 1, 512, 2048, 2048, 0, 0, 0, 0, 0, 0, 0);
        sgemm<64, 0, false, 0><<<dim3(8, 16, 4), 256, 0, stream>>>(
            w.ffn, e_W2 + (long long)i * cDFF * cD, w.parts, nullptr, nullptr, nullptr, nullptr, nullptr,
            2048, 4, 1, 2048, 512, 512, 0, 0, 0, 0, 0, 0, M1);
        reduce_flat<false><<<dim3(1024), 256, 0, stream>>>(w.parts, w.t0, M1, 4, M1, nullptr, 0, w.t1);
    }
    // w.t0 = enc_repr

    // ---- decoder ----
    for (int i = 0; i < 2; ++i) {
        ln_kernel<<<lnGrid, 256, 0, stream>>>(w.t3, w.t1);
        run_mha(stream, w, 2 + i, w.t1, w.t1,
                ds_WO + (long long)i * cD * cD, ds_bO + i * cD,
                w.pin, w.pin, /*causal=*/true, w.t1, w.t2);     // pad_in both (preserved bug)
        ln_kernel<<<lnGrid, 256, 0, stream>>>(w.t2, w.t1);
        run_mha(stream, w, 4 + i, w.t1, w.t0,
                dc_WO + (long long)i * cD * cD, dc_bO + i * cD,
                w.pout, w.pin, /*causal=*/false, w.t1, w.t2);
        ln_kernel<<<lnGrid, 256, 0, stream>>>(w.t2, w.t1);
        sgemm<64, 0, true, 0><<<dim3(32, 16, 1), 256, 0, stream>>>(
            w.t1, d_W1 + (long long)i * cD * cDFF, w.ffn, nullptr, nullptr, nullptr, nullptr, nullptr,
            512, 1, 1, 512, 2048, 2048, 0, 0, 0, 0, 0, 0, 0);
        sgemm<64, 0, false, 0><<<dim3(8, 16, 4), 256, 0, stream>>>(
            w.ffn, d_W2 + (long long)i * cDFF * cD, w.parts, nullptr, nullptr, nullptr, nullptr, nullptr,
            2048, 4, 1, 2048, 512, 512, 0, 0, 0, 0, 0, 0, M1);
        reduce_flat<false><<<dim3(1024), 256, 0, stream>>>(w.parts, w.t3, M1, 4, M1, nullptr, 0, w.t1);
    }

    final_kernel<<<dim3(cB * (cS - 1)), 256, 0, stream>>>(w.t3, w.pout, Y);
}

// Round 9
// 1814.834 us; speedup vs baseline: 1.1892x; 1.1892x over previous
//
#include <hip/hip_runtime.h>
#include <cstdint>
#include <cstddef>

// Problem constants (fixed by the reference)
constexpr int cB = 2, cS = 1024, cD = 512, cH = 8, cDK = 64, cDFF = 2048;
constexpr int cBS = cB * cS;
constexpr float kNEG = -1e19f;

// NUMERICS RULE (learned R5): the batch-dim layer_norm is a ±0.707 step around
// diff=0; changing any GEMM's fp32 accumulation order flips near-zero diffs and
// cascades O(1) errors to the output. Every GEMM keeps a single fmaf chain with
// k strictly ascending (R4-verified bit pattern). Split-K groupings frozen
// (PV=4, WO=4, FFN2=4, crossQ=4, crossKV=2). Tile shape (BM/BN) is free — it
// does not touch the per-output chain. Fused softmax applies bit-identical ops
// (expf(x-m)*inv on identical stats) -> P bits unchanged (R7-verified).
// STRUCTURE RULE (learned R7): no explicit dbuf/reg-staging — VGPR 36->136 and
// 2x LDS halved occupancy and cost +285us. Single-buffer + more blocks/CU wins.

__device__ __forceinline__ float gelu_f(float x)
{
    return 0.5f * x * (1.0f + erff(x * 0.70710678118654752440f));
}

// fused-softmax element transform (PVF: 1 = non-causal, 2 = causal)
template<int PVF>
__device__ __forceinline__ float pvf1(float x, bool masked, int q, int kabs, float rm, float riv)
{
    if (PVF == 2) masked = masked || (q < kabs);
    if (masked) x += kNEG;
    if (PVF == 1) x *= 0.125f;
    return expf(x - rm) * riv;
}

// ============================ SGEMM (fp32 vector, single-buffer) ============================
// Tile BM(64|128) x BN(64|128), BK=16, 256 threads, (BM/16)x(BN/16) microtile.
// MODE: 0 = NN (A[m][k], B[k][n]); 1 = TA (A[k][m], B[k][n]); 2 = TB (A[m][k], B[n][k]).
// PVF != 0 (requires MODE==1): A is raw scoresT; softmax applied during staging
// using per-row stats (m, inv) from sstats_kernel — bit-identical to separate softmax.
// z = ((g1*G2+g2)*KS + kc); split-K writes plane kc at C + kc*plane.
template<int BM, int BN, int MODE, bool GELU, int PVF>
__global__ __launch_bounds__(256) void sgemm(
    const float* __restrict__ A, const float* __restrict__ B, float* __restrict__ C,
    const float* __restrict__ bias, const float* __restrict__ resid,
    const float* __restrict__ stats, const unsigned char* __restrict__ padq,
    const unsigned char* __restrict__ padk,
    int K, int KS, int G2, int lda, int ldb, int ldc,
    long long a1, long long a2, long long b1, long long b2,
    long long c1, long long c2, long long plane)
{
    constexpr int BK = 16;
    constexpr int AP = BM + 4, BP = BN + 4;
    constexpr int MR = BM / 16;                      // rows per thread (4 or 8)
    constexpr int NR = BN / 16;                      // cols per thread (4 or 8)
    __shared__ float As[BK][AP];
    __shared__ float Bs[BK][BP];

    const int z = blockIdx.z;
    const int kc = z % KS;
    const int zz = z / KS;
    const int g1 = zz / G2, g2 = zz % G2;
    const float* Ab = A + (long long)g1 * a1 + (long long)g2 * a2;
    const float* Bb = B + (long long)g1 * b1 + (long long)g2 * b2;
    float* Cb = C + (long long)g1 * c1 + (long long)g2 * c2 + (long long)kc * plane;
    const int klen = K / KS, kbase = kc * klen;
    const int m0 = blockIdx.y * BM, n0 = blockIdx.x * BN;
    const int t = threadIdx.x, tx = t & 15, ty = t >> 4;

    const float* stm = nullptr;
    const unsigned char* pqB = nullptr;
    const unsigned char* pkB = nullptr;
    if (PVF) {
        stm = stats + (long long)zz * 2048;          // zz = b*8+h; [k]{m,inv}
        pqB = padq + (long long)g1 * cS;
        pkB = padk + (long long)g1 * cS;
    }

    float acc[MR][NR];
    #pragma unroll
    for (int i = 0; i < MR; ++i)
        #pragma unroll
        for (int j = 0; j < NR; ++j) acc[i][j] = 0.f;

    for (int k0 = kbase; k0 < kbase + klen; k0 += BK) {
        // ---- stage A (BMx16 = BM/64 float4/thread) ----
        if (MODE == 1) {                              // TA: A stored [K][M]
            #pragma unroll
            for (int r = 0; r < BM / 64; ++r) {
                const int c = r * 256 + t;
                const int kk = c / (BM / 4), m4 = c % (BM / 4);
                float4 v = *(const float4*)&Ab[(long long)(k0 + kk) * lda + m0 + m4 * 4];
                if (PVF) {
                    const int kabs = k0 + kk, q0 = m0 + m4 * 4;
                    const float2 st = *(const float2*)&stm[kabs * 2];
                    const bool pk = pkB[kabs] != 0;
                    const uchar4 pq = *(const uchar4*)&pqB[q0];
                    v.x = pvf1<PVF>(v.x, pk || pq.x, q0 + 0, kabs, st.x, st.y);
                    v.y = pvf1<PVF>(v.y, pk || pq.y, q0 + 1, kabs, st.x, st.y);
                    v.z = pvf1<PVF>(v.z, pk || pq.z, q0 + 2, kabs, st.x, st.y);
                    v.w = pvf1<PVF>(v.w, pk || pq.w, q0 + 3, kabs, st.x, st.y);
                }
                *(float4*)&As[kk][m4 * 4] = v;
            }
        } else {                                      // A stored [M][K]
            #pragma unroll
            for (int r = 0; r < BM / 64; ++r) {
                const int c = r * 256 + t, kq = c & 3, mm = c >> 2;
                float4 v = *(const float4*)&Ab[(long long)(m0 + mm) * lda + k0 + kq * 4];
                As[kq * 4 + 0][mm] = v.x; As[kq * 4 + 1][mm] = v.y;
                As[kq * 4 + 2][mm] = v.z; As[kq * 4 + 3][mm] = v.w;
            }
        }
        // ---- stage B (BNx16 = BN/64 float4/thread) ----
        if (MODE == 2) {                              // TB: B stored [N][K]
            #pragma unroll
            for (int r = 0; r < BN / 64; ++r) {
                const int c = r * 256 + t, kq = c & 3, nn = c >> 2;
                float4 v = *(const float4*)&Bb[(long long)(n0 + nn) * ldb + k0 + kq * 4];
                Bs[kq * 4 + 0][nn] = v.x; Bs[kq * 4 + 1][nn] = v.y;
                Bs[kq * 4 + 2][nn] = v.z; Bs[kq * 4 + 3][nn] = v.w;
            }
        } else {                                      // B stored [K][N]
            #pragma unroll
            for (int r = 0; r < BN / 64; ++r) {
                const int c = r * 256 + t, n4 = c & (BN / 4 - 1), kk = c / (BN / 4);
                *(float4*)&Bs[kk][n4 * 4] =
                    *(const float4*)&Bb[(long long)(k0 + kk) * ldb + n0 + n4 * 4];
            }
        }
        __syncthreads();
        #pragma unroll
        for (int kk = 0; kk < BK; ++kk) {
            float a[MR], b[NR];
            #pragma unroll
            for (int g = 0; g < MR / 4; ++g)
                *(float4*)&a[g * 4] = *(const float4*)&As[kk][ty * MR + g * 4]; // broadcast: free
            *(float4*)&b[0] = *(const float4*)&Bs[kk][tx * 4];                  // 2-addr/bank: free
            if (NR == 8)
                *(float4*)&b[4] = *(const float4*)&Bs[kk][64 + tx * 4];
            #pragma unroll
            for (int i = 0; i < MR; ++i)
                #pragma unroll
                for (int j = 0; j < NR; ++j)
                    acc[i][j] = fmaf(a[i], b[j], acc[i][j]);
        }
        __syncthreads();
    }

    // ---- epilogue ----
    #pragma unroll
    for (int i = 0; i < MR; ++i) {
        const int row = m0 + ty * MR + i;
        #pragma unroll
        for (int g = 0; g < NR / 4; ++g) {
            const int col = n0 + g * 64 + tx * 4;
            float4 v;
            v.x = acc[i][g * 4 + 0]; v.y = acc[i][g * 4 + 1];
            v.z = acc[i][g * 4 + 2]; v.w = acc[i][g * 4 + 3];
            if (bias) {
                v.x += bias[col + 0]; v.y += bias[col + 1];
                v.z += bias[col + 2]; v.w += bias[col + 3];
            }
            if (GELU) {
                v.x = gelu_f(v.x); v.y = gelu_f(v.y);
                v.z = gelu_f(v.z); v.w = gelu_f(v.w);
            }
            const long long idx = (long long)row * ldc + col;
            if (resid) {
                float4 rr = *(const float4*)&resid[idx];
                v.x += rr.x; v.y += rr.y; v.z += rr.z; v.w += rr.w;
            }
            *(float4*)&Cb[idx] = v;
        }
    }
}

// ============================ split-K reduces ============================
template<bool GELU>
__global__ __launch_bounds__(256) void reduce_flat(
    const float* __restrict__ parts, float* __restrict__ out, long long n,
    int ks, long long plane, const float* __restrict__ bias, int ldcMask,
    const float* __restrict__ resid)
{
    const long long i = ((long long)blockIdx.x * 256 + threadIdx.x) * 4;
    if (i >= n) return;
    float4 s = {0.f, 0.f, 0.f, 0.f};
    for (int z = 0; z < ks; ++z) {
        float4 v = *(const float4*)&parts[(long long)z * plane + i];
        s.x += v.x; s.y += v.y; s.z += v.z; s.w += v.w;
    }
    if (bias) {
        const int col = (int)(i & ldcMask);
        s.x += bias[col + 0]; s.y += bias[col + 1];
        s.z += bias[col + 2]; s.w += bias[col + 3];
    }
    if (GELU) {
        s.x = gelu_f(s.x); s.y = gelu_f(s.y);
        s.z = gelu_f(s.z); s.w = gelu_f(s.w);
    }
    if (resid) {
        float4 rr = *(const float4*)&resid[i];
        s.x += rr.x; s.y += rr.y; s.z += rr.z; s.w += rr.w;
    }
    *(float4*)&out[i] = s;
}

__global__ __launch_bounds__(256) void reduce_scatter(
    const float* __restrict__ parts, float* __restrict__ out, long long n,
    int ks, long long plane, int logN, int maskN, int ldcOut, int colBase)
{
    const long long i = ((long long)blockIdx.x * 256 + threadIdx.x) * 4;
    if (i >= n) return;
    float4 s = {0.f, 0.f, 0.f, 0.f};
    for (int z = 0; z < ks; ++z) {
        float4 v = *(const float4*)&parts[(long long)z * plane + i];
        s.x += v.x; s.y += v.y; s.z += v.z; s.w += v.w;
    }
    const long long row = i >> logN;
    const int col = (int)(i & maskN);
    *(float4*)&out[row * ldcOut + colBase + col] = s;
}

// ============================ Wc3 (tiled GEMM, all 6 MHAs, one dispatch) ============
__global__ __launch_bounds__(256) void wct_gemm(
    const float* __restrict__ ec, const float* __restrict__ eh,
    const float* __restrict__ dsc, const float* __restrict__ dsh,
    const float* __restrict__ dcc, const float* __restrict__ dch,
    float* __restrict__ Wc3)
{
    constexpr long long LWH = 3LL * 512 * 64;
    __shared__ float As[16][132];
    __shared__ float Bs[16][68];
    const int bid = blockIdx.x;
    const int mt = bid & 3;
    const int zp = bid >> 2;
    const int zi = zp / 24;
    const int ph = zp % 24;
    const int p = ph >> 3, h = ph & 7;
    const int l = zi & 1;
    const float* comb = (zi < 2) ? ec : (zi < 4) ? dsc : dcc;
    const float* head = (zi < 2) ? eh : (zi < 4) ? dsh : dch;
    const float* Ab = comb + l * LWH + (long long)p * 512 * 64 + mt * 128 * 64;
    const float* Bb = head + l * LWH + (long long)ph * 4096;
    float* Cb = Wc3 + (long long)zi * 512 * 1536 + (long long)mt * 128 * 1536 + p * 512 + h * 64;
    const int t = threadIdx.x, tx = t & 15, ty = t >> 4;

    float acc[8][4];
    #pragma unroll
    for (int i = 0; i < 8; ++i)
        #pragma unroll
        for (int j = 0; j < 4; ++j) acc[i][j] = 0.f;

    for (int k0 = 0; k0 < 64; k0 += 16) {
        #pragma unroll
        for (int r = 0; r < 2; ++r) {
            const int c = r * 256 + t, kq = c & 3, mm = c >> 2;
            float4 v = *(const float4*)&Ab[mm * 64 + k0 + kq * 4];
            As[kq * 4 + 0][mm] = v.x; As[kq * 4 + 1][mm] = v.y;
            As[kq * 4 + 2][mm] = v.z; As[kq * 4 + 3][mm] = v.w;
        }
        {
            const int n4 = t & 15, kk = t >> 4;
            *(float4*)&Bs[kk][n4 * 4] = *(const float4*)&Bb[(k0 + kk) * 64 + n4 * 4];
        }
        __syncthreads();
        #pragma unroll
        for (int kk = 0; kk < 16; ++kk) {
            float a[8];
            *(float4*)&a[0] = *(const float4*)&As[kk][ty * 8];
            *(float4*)&a[4] = *(const float4*)&As[kk][ty * 8 + 4];
            float4 b4 = *(const float4*)&Bs[kk][tx * 4];
            const float b[4] = {b4.x, b4.y, b4.z, b4.w};
            #pragma unroll
            for (int i = 0; i < 8; ++i)
                #pragma unroll
                for (int j = 0; j < 4; ++j)
                    acc[i][j] = fmaf(a[i], b[j], acc[i][j]);
        }
        __syncthreads();
    }
    #pragma unroll
    for (int i = 0; i < 8; ++i) {
        const int row = ty * 8 + i;
        float4 v;
        v.x = acc[i][0]; v.y = acc[i][1]; v.z = acc[i][2]; v.w = acc[i][3];
        *(float4*)&Cb[(long long)row * 1536 + tx * 4] = v;
    }
}

// ============================ softmax STATS over QUERY dim ============================
// Bit-identical reductions to the R6 softmax kernel; writes {m, inv} per row.
template<bool CAUSAL>
__global__ __launch_bounds__(256) void sstats_kernel(
    const float* __restrict__ sc, const unsigned char* __restrict__ padq,
    const unsigned char* __restrict__ padk, float scale, float* __restrict__ stats)
{
    const int r = blockIdx.x;             // (b*H + h)*S + k
    const int k = r & (cS - 1);
    const int b = r / (cH * cS);
    const float* row = sc + (long long)r * cS;
    const bool pk = padk[b * cS + k] != 0;
    const int tid = threadIdx.x;
    float4 v4 = reinterpret_cast<const float4*>(row)[tid];
    float vals[4] = {v4.x, v4.y, v4.z, v4.w};
    #pragma unroll
    for (int u = 0; u < 4; ++u) {
        const int q = tid * 4 + u;
        bool masked = pk || (padq[b * cS + q] != 0);
        if (CAUSAL) masked = masked || (q < k);
        float x = vals[u];
        if (masked) x += kNEG;
        if (!CAUSAL) x *= scale;
        vals[u] = x;
    }
    float m = fmaxf(fmaxf(vals[0], vals[1]), fmaxf(vals[2], vals[3]));
    #pragma unroll
    for (int off = 32; off > 0; off >>= 1) m = fmaxf(m, __shfl_down(m, off));
    __shared__ float red[8];
    if ((tid & 63) == 0) red[tid >> 6] = m;
    __syncthreads();
    const float rm = fmaxf(fmaxf(red[0], red[1]), fmaxf(red[2], red[3]));
    float e[4], s = 0.f;
    #pragma unroll
    for (int u = 0; u < 4; ++u) { e[u] = expf(vals[u] - rm); s += e[u]; }
    #pragma unroll
    for (int off = 32; off > 0; off >>= 1) s += __shfl_down(s, off);
    if ((tid & 63) == 0) red[4 + (tid >> 6)] = s;
    __syncthreads();
    if (tid == 0) {
        float inv = 1.0f / (red[4] + red[5] + red[6] + red[7]);
        if (CAUSAL) inv *= scale;
        stats[2 * r] = rm;
        stats[2 * r + 1] = inv;
    }
}

// ============================ batch-dim layer norm (B=2 closed form) ============================
__global__ __launch_bounds__(256) void ln_kernel(const float* __restrict__ x, float* __restrict__ out)
{
    const long long idx = ((long long)blockIdx.x * 256 + threadIdx.x) * 4;
    float4 x0 = *(const float4*)&x[idx];
    float4 x1 = *(const float4*)&x[idx + (long long)cS * cD];
    float4 o;
    {
        const float d0 = x0.x - x1.x; o.x = (0.5f * d0) / (fabsf(d0) * 0.70710678f + 1e-4f);
        const float d1 = x0.y - x1.y; o.y = (0.5f * d1) / (fabsf(d1) * 0.70710678f + 1e-4f);
        const float d2 = x0.z - x1.z; o.z = (0.5f * d2) / (fabsf(d2) * 0.70710678f + 1e-4f);
        const float d3 = x0.w - x1.w; o.w = (0.5f * d3) / (fabsf(d3) * 0.70710678f + 1e-4f);
    }
    *(float4*)&out[idx] = o;
    float4 n;
    n.x = -o.x; n.y = -o.y; n.z = -o.z; n.w = -o.w;
    *(float4*)&out[idx + (long long)cS * cD] = n;
}

// ============================ padding masks ============================
__global__ __launch_bounds__(256) void pad_in_kernel(const float* __restrict__ X, unsigned char* __restrict__ pad)
{
    const int r = blockIdx.x;
    const float* row = X + (long long)r * cD;
    const int tid = threadIdx.x;
    const bool nz = (row[tid] != 0.f) | (row[tid + 256] != 0.f);
    unsigned long long w = __ballot(nz);
    __shared__ unsigned long long sh[4];
    if ((tid & 63) == 0) sh[tid >> 6] = w;
    __syncthreads();
    if (tid == 0) pad[r] = ((sh[0] | sh[1] | sh[2] | sh[3]) == 0ULL) ? 1 : 0;
}

__global__ __launch_bounds__(256) void pad_dec_kernel(const float* __restrict__ outp, unsigned char* __restrict__ pad)
{
    const int r = blockIdx.x;
    const int s = r & (cS - 1);
    const int b = r >> 10;
    if (s == 0) { if (threadIdx.x == 0) pad[r] = 0; return; }
    const float* row = outp + ((long long)b * (cS - 1) + (s - 1)) * cD;
    const int tid = threadIdx.x;
    const bool nz = (row[tid] != 0.f) | (row[tid + 256] != 0.f);
    unsigned long long w = __ballot(nz);
    __shared__ unsigned long long sh[4];
    if ((tid & 63) == 0) sh[tid >> 6] = w;
    __syncthreads();
    if (tid == 0) pad[r] = ((sh[0] | sh[1] | sh[2] | sh[3]) == 0ULL) ? 1 : 0;
}

// ============================ positional encoding ============================
__device__ __forceinline__ float pe_val(int s, int d)
{
    const int i2 = d & ~1;
    const float dv = powf(10000.0f, -(float)i2 / (float)cD);
    const float ang = (float)s * dv;
    return (d & 1) ? cosf(ang) : sinf(ang);
}

__global__ __launch_bounds__(256) void posenc_enc_kernel(const float* __restrict__ X, float* __restrict__ out)
{
    const int r = blockIdx.x;
    const int s = r & (cS - 1);
    const int tid = threadIdx.x;
    #pragma unroll
    for (int u = 0; u < 2; ++u) {
        const int d = tid + 256 * u;
        out[(long long)r * cD + d] = X[(long long)r * cD + d] + pe_val(s, d);
    }
}

__global__ __launch_bounds__(256) void posenc_dec_kernel(const float* __restrict__ outp, float* __restrict__ out)
{
    const int r = blockIdx.x;
    const int s = r & (cS - 1);
    const int b = r >> 10;
    const int tid = threadIdx.x;
    #pragma unroll
    for (int u = 0; u < 2; ++u) {
        const int d = tid + 256 * u;
        const float base = (s == 0) ? 1.0f : outp[((long long)b * (cS - 1) + (s - 1)) * cD + d];
        out[(long long)r * cD + d] = base + pe_val(s, d);
    }
}

// ============================ final masked slice ============================
__global__ __launch_bounds__(256) void final_kernel(const float* __restrict__ cur,
                                                    const unsigned char* __restrict__ pad,
                                                    float* __restrict__ out)
{
    const int r = blockIdx.x;
    const int b = r / (cS - 1);
    const int s = r - b * (cS - 1) + 1;
    const int tid = threadIdx.x;
    const bool p = pad[b * cS + s] != 0;
    #pragma unroll
    for (int u = 0; u < 2; ++u) {
        const int d = tid + 256 * u;
        out[(long long)r * cD + d] = p ? 0.0f : cur[((long long)b * cS + s) * cD + d];
    }
}

// ============================ host orchestration ============================
struct Ws {
    float *t0, *t1, *t2, *t3, *wc3a, *qkv, *att, *parts, *sc, *ffn, *stats;
    unsigned char *pin, *pout;
};

static void run_mha(hipStream_t st, const Ws& w, int mhaIdx,
                    const float* xq, const float* xkv,
                    const float* WO, const float* bO,
                    const unsigned char* padq, const unsigned char* padk,
                    bool causal, const float* resid, float* outR)
{
    const long long M1 = 1048576;
    const float* wc3 = w.wc3a + (long long)mhaIdx * 512 * 1536;
    if (xq == xkv) {
        // fused QKV (NN, 128x64, KS=1, grid 384)
        sgemm<128, 64, 0, false, 0><<<dim3(24, 16, 1), 256, 0, st>>>(
            xq, wc3, w.qkv, nullptr, nullptr, nullptr, nullptr, nullptr,
            512, 1, 1, 512, 1536, 1536, 0, 0, 0, 0, 0, 0, 0);
    } else {
        // cross: Q (split-K=4), K/V (split-K=2)
        sgemm<128, 64, 0, false, 0><<<dim3(8, 16, 4), 256, 0, st>>>(
            xq, wc3, w.parts, nullptr, nullptr, nullptr, nullptr, nullptr,
            512, 4, 1, 512, 1536, 512, 0, 0, 0, 0, 0, 0, M1);
        reduce_scatter<<<dim3(1024), 256, 0, st>>>(w.parts, w.qkv, M1, 4, M1, 9, 511, 1536, 0);
        sgemm<128, 64, 0, false, 0><<<dim3(16, 16, 2), 256, 0, st>>>(
            xkv, wc3 + 512, w.parts, nullptr, nullptr, nullptr, nullptr, nullptr,
            512, 2, 1, 512, 1536, 1024, 0, 0, 0, 0, 0, 0, 2 * M1);
        reduce_scatter<<<dim3(2048), 256, 0, st>>>(w.parts, w.qkv, 2 * M1, 2, 2 * M1, 10, 1023, 1536, 512);
    }
    // scoresT[b,h][k][q] = K . Q (TB, 128x128, grid 1024)
    sgemm<128, 128, 2, false, 0><<<dim3(8, 8, 16), 256, 0, st>>>(
        w.qkv + 512, w.qkv, w.sc, nullptr, nullptr, nullptr, nullptr, nullptr,
        64, 1, 8, 1536, 1536, 1024,
        1024LL * 1536, 64, 1024LL * 1536, 64, 8 * M1, M1, 0);
    // softmax stats over q (bit-identical reductions; 64 MB read, 32 KB write)
    {
        dim3 g(cB * cH * cS), blk(256);
        if (causal) sstats_kernel<true><<<g, blk, 0, st>>>(w.sc, padq, padk, 0.125f, w.stats);
        else        sstats_kernel<false><<<g, blk, 0, st>>>(w.sc, padq, padk, 0.125f, w.stats);
    }
    // PV (TA x NN, 64x64 tile for 1024 blocks, split-K=4) with fused softmax staging
    if (causal) {
        sgemm<64, 64, 1, false, 2><<<dim3(1, 16, 64), 256, 0, st>>>(
            w.sc, w.qkv + 1024, w.parts, nullptr, nullptr, w.stats, padq, padk,
            1024, 4, 8, 1024, 1536, 512,
            8 * M1, M1, 1024LL * 1536, 64, 1024LL * 512, 64, M1);
    } else {
        sgemm<64, 64, 1, false, 1><<<dim3(1, 16, 64), 256, 0, st>>>(
            w.sc, w.qkv + 1024, w.parts, nullptr, nullptr, w.stats, padq, padk,
            1024, 4, 8, 1024, 1536, 512,
            8 * M1, M1, 1024LL * 1536, 64, 1024LL * 512, 64, M1);
    }
    reduce_flat<false><<<dim3(1024), 256, 0, st>>>(w.parts, w.att, M1, 4, M1, nullptr, 0, nullptr);
    // WO (NN, 128x64, split-K=4, grid 512)
    sgemm<128, 64, 0, false, 0><<<dim3(8, 16, 4), 256, 0, st>>>(
        w.att, WO, w.parts, nullptr, nullptr, nullptr, nullptr, nullptr,
        512, 4, 1, 512, 512, 512, 0, 0, 0, 0, 0, 0, M1);
    reduce_flat<false><<<dim3(1024), 256, 0, st>>>(w.parts, outR, M1, 4, M1, bO, 511, resid);
}

extern "C" void kernel_launch(void* const* d_in, const int* in_sizes, int n_in,
                              void* d_out, int out_size, void* d_ws, size_t ws_size,
                              hipStream_t stream)
{
    const float* X       = (const float*)d_in[0];
    const float* outp    = (const float*)d_in[1];
    const float* e_comb  = (const float*)d_in[2];
    const float* e_head  = (const float*)d_in[3];
    const float* e_WO    = (const float*)d_in[4];
    const float* e_bO    = (const float*)d_in[5];
    const float* e_W1    = (const float*)d_in[6];
    const float* e_W2    = (const float*)d_in[7];
    const float* ds_comb = (const float*)d_in[8];
    const float* ds_head = (const float*)d_in[9];
    const float* ds_WO   = (const float*)d_in[10];
    const float* ds_bO   = (const float*)d_in[11];
    const float* dc_comb = (const float*)d_in[12];
    const float* dc_head = (const float*)d_in[13];
    const float* dc_WO   = (const float*)d_in[14];
    const float* dc_bO   = (const float*)d_in[15];
    const float* d_W1    = (const float*)d_in[16];
    const float* d_W2    = (const float*)d_in[17];
    float* Y = (float*)d_out;

    Ws w;
    float* p = (float*)d_ws;
    const long long M1 = 1048576;
    w.t0   = p; p += M1;
    w.t1   = p; p += M1;
    w.t2   = p; p += M1;
    w.t3   = p; p += M1;
    w.wc3a = p; p += 6LL * 512 * 1536;      // 4,718,592
    w.qkv  = p; p += 2048LL * 1536;         // 3,145,728
    w.att  = p; p += M1;
    w.parts= p; p += 4 * M1;                // split-K compact planes (PV/WO/FFN2/cross)
    w.sc   = p; p += 16LL * M1;             // 64 MB scores
    w.ffn  = w.sc;                          // [2048][2048] overlays sc[0..4M1]
    w.stats= p; p += 2LL * cB * cH * cS;    // 32768 floats: {m, inv} per score row
    w.pin  = (unsigned char*)p;
    w.pout = w.pin + cB * cS;

    // ---- prep ----
    pad_in_kernel <<<dim3(cB * cS), 256, 0, stream>>>(X, w.pin);
    pad_dec_kernel<<<dim3(cB * cS), 256, 0, stream>>>(outp, w.pout);
    posenc_enc_kernel<<<dim3(cB * cS), 256, 0, stream>>>(X, w.t0);
    posenc_dec_kernel<<<dim3(cB * cS), 256, 0, stream>>>(outp, w.t3);
    wct_gemm<<<dim3(576), 256, 0, stream>>>(e_comb, e_head, ds_comb, ds_head, dc_comb, dc_head, w.wc3a);

    const dim3 lnGrid(cS * cD / 1024);

    // ---- encoder ----
    for (int i = 0; i < 2; ++i) {
        ln_kernel<<<lnGrid, 256, 0, stream>>>(w.t0, w.t1);
        run_mha(stream, w, i, w.t1, w.t1,
                e_WO + (long long)i * cD * cD, e_bO + i * cD,
                w.pin, w.pin, false, w.t1, w.t2);
        ln_kernel<<<lnGrid, 256, 0, stream>>>(w.t2, w.t1);
        sgemm<128, 64, 0, true, 0><<<dim3(32, 16, 1), 256, 0, stream>>>(
            w.t1, e_W1 + (long long)i * cD * cDFF, w.ffn, nullptr, nullptr, nullptr, nullptr, nullptr,
            512, 1, 1, 512, 2048, 2048, 0, 0, 0, 0, 0, 0, 0);
        sgemm<128, 64, 0, false, 0><<<dim3(8, 16, 4), 256, 0, stream>>>(
            w.ffn, e_W2 + (long long)i * cDFF * cD, w.parts, nullptr, nullptr, nullptr, nullptr, nullptr,
            2048, 4, 1, 2048, 512, 512, 0, 0, 0, 0, 0, 0, M1);
        reduce_flat<false><<<dim3(1024), 256, 0, stream>>>(w.parts, w.t0, M1, 4, M1, nullptr, 0, w.t1);
    }
    // w.t0 = enc_repr

    // ---- decoder ----
    for (int i = 0; i < 2; ++i) {
        ln_kernel<<<lnGrid, 256, 0, stream>>>(w.t3, w.t1);
        run_mha(stream, w, 2 + i, w.t1, w.t1,
                ds_WO + (long long)i * cD * cD, ds_bO + i * cD,
                w.pin, w.pin, /*causal=*/true, w.t1, w.t2);     // pad_in both (preserved bug)
        ln_kernel<<<lnGrid, 256, 0, stream>>>(w.t2, w.t1);
        run_mha(stream, w, 4 + i, w.t1, w.t0,
                dc_WO + (long long)i * cD * cD, dc_bO + i * cD,
                w.pout, w.pin, /*causal=*/false, w.t1, w.t2);
        ln_kernel<<<lnGrid, 256, 0, stream>>>(w.t2, w.t1);
        sgemm<128, 64, 0, true, 0><<<dim3(32, 16, 1), 256, 0, stream>>>(
            w.t1, d_W1 + (long long)i * cD * cDFF, w.ffn, nullptr, nullptr, nullptr, nullptr, nullptr,
            512, 1, 1, 512, 2048, 2048, 0, 0, 0, 0, 0, 0, 0);
        sgemm<128, 64, 0, false, 0><<<dim3(8, 16, 4), 256, 0, stream>>>(
            w.ffn, d_W2 + (long long)i * cDFF * cD, w.parts, nullptr, nullptr, nullptr, nullptr, nullptr,
            2048, 4, 1, 2048, 512, 512, 0, 0, 0, 0, 0, 0, M1);
        reduce_flat<false><<<dim3(1024), 256, 0, stream>>>(w.parts, w.t3, M1, 4, M1, nullptr, 0, w.t1);
    }

    final_kernel<<<dim3(cB * (cS - 1)), 256, 0, stream>>>(w.t3, w.pout, Y);
}